// Round 1
// baseline (288.550 us; speedup 1.0000x reference)
//
#include <hip/hip_runtime.h>

typedef __bf16 bf16;
typedef __bf16 bf16x4 __attribute__((ext_vector_type(4)));
typedef __bf16 bf16x8 __attribute__((ext_vector_type(8)));
typedef float f32x4 __attribute__((ext_vector_type(4)));

#define DIM   2048
#define BQ    128
#define KVL   4096
#define KVT   4224   // KV_LEN + Q_LEN
#define M_TOT 1024   // B * Q_LEN

// Swizzled element offset inside a [ROWS][64]-bf16 LDS tile (128B rows).
// XOR bits 3..5 of the element column with row&7 -> bank-conflict-free-ish
// ds_read_b128 fragment reads (G4 fix for 128B-stride rows).
__device__ __forceinline__ int swz(int row, int col) {
  return row * 64 + (col ^ ((row & 7) << 3));
}

// ---- staging: global fp32 [ROWS][ld] -> bf16 LDS tile [ROWS][64] ----
template<int ROWS, int NTHR>
__device__ __forceinline__ void stage_f32(const float* __restrict__ src, int ld,
                                          bf16* dst, int tid) {
  constexpr int ITERS = (ROWS * 16) / NTHR;
  const int r0 = tid >> 4;
  const int c  = (tid & 15) * 4;
  #pragma unroll
  for (int j = 0; j < ITERS; ++j) {
    int row = j * (NTHR / 16) + r0;
    const float4 v = *reinterpret_cast<const float4*>(src + (size_t)row * ld + c);
    bf16x4 b;
    b[0] = (bf16)v.x; b[1] = (bf16)v.y; b[2] = (bf16)v.z; b[3] = (bf16)v.w;
    *reinterpret_cast<bf16x4*>(dst + swz(row, c)) = b;
  }
}

// ---- staging: global bf16 [ROWS][ld] -> bf16 LDS tile [ROWS][64] ----
template<int ROWS, int NTHR>
__device__ __forceinline__ void stage_bf16(const bf16* __restrict__ src, int ld,
                                           bf16* dst, int tid) {
  constexpr int ITERS = (ROWS * 8) / NTHR;
  const int r0 = tid >> 3;
  const int c  = (tid & 7) * 8;
  #pragma unroll
  for (int j = 0; j < ITERS; ++j) {
    int row = j * (NTHR / 8) + r0;
    bf16x8 v = *reinterpret_cast<const bf16x8*>(src + (size_t)row * ld + c);
    *reinterpret_cast<bf16x8*>(dst + swz(row, c)) = v;
  }
}

// ---- wave tile: MF x NF fragments of 16x16, K-depth 64 (2 mfma k-steps) ----
template<int MF, int NF>
__device__ __forceinline__ void mma_tile(const bf16* As, const bf16* Bs,
                                         f32x4 (&acc)[MF][NF], int l, int wm, int wn) {
  const int ar = l & 15;
  const int ak = (l >> 4) * 8;
  bf16x8 a[MF][2], b[NF][2];
  #pragma unroll
  for (int mi = 0; mi < MF; ++mi)
    #pragma unroll
    for (int kk = 0; kk < 2; ++kk) {
      int row = wm + mi * 16 + ar;
      a[mi][kk] = *reinterpret_cast<const bf16x8*>(As + swz(row, kk * 32 + ak));
    }
  #pragma unroll
  for (int ni = 0; ni < NF; ++ni)
    #pragma unroll
    for (int kk = 0; kk < 2; ++kk) {
      int row = wn + ni * 16 + ar;
      b[ni][kk] = *reinterpret_cast<const bf16x8*>(Bs + swz(row, kk * 32 + ak));
    }
  #pragma unroll
  for (int kk = 0; kk < 2; ++kk)
    #pragma unroll
    for (int mi = 0; mi < MF; ++mi)
      #pragma unroll
      for (int ni = 0; ni < NF; ++ni)
        acc[mi][ni] = __builtin_amdgcn_mfma_f32_16x16x32_bf16(
            a[mi][kk], b[ni][kk], acc[mi][ni], 0, 0, 0);
}

// ================= Kernel A: q/k/v projections (x @ W^T) =================
// grid (96, 8): 96 n-tiles of 64 over the 3 stacked weights, 8 m-tiles of 128.
__global__ __launch_bounds__(256) void k_qkv(const float* __restrict__ x,
    const float* __restrict__ wq, const float* __restrict__ wk,
    const float* __restrict__ wv,
    bf16* __restrict__ qb, bf16* __restrict__ kb, bf16* __restrict__ vb) {
  __shared__ bf16 As[128 * 64];
  __shared__ bf16 Bs[64 * 64];
  const int nt = blockIdx.x;
  const int mt = blockIdx.y;
  const int w  = nt >> 5;
  const int nloc = (nt & 31) * 64;
  const float* __restrict__ W = (w == 0) ? wq : (w == 1) ? wk : wv;
  bf16* __restrict__ O = (w == 0) ? qb : (w == 1) ? kb : vb;
  const int m0 = mt * 128;
  const int tid = threadIdx.x;
  const int l = tid & 63, wid = tid >> 6;
  const int wm = (wid >> 1) * 64, wn = (wid & 1) * 32;
  f32x4 acc[4][2] = {};
  for (int kt = 0; kt < DIM / 64; ++kt) {
    const int k0 = kt * 64;
    __syncthreads();
    stage_f32<128, 256>(x + (size_t)m0 * DIM + k0, DIM, As, tid);
    stage_f32<64, 256>(W + (size_t)nloc * DIM + k0, DIM, Bs, tid);
    __syncthreads();
    mma_tile<4, 2>(As, Bs, acc, l, wm, wn);
  }
  const int rr = (l >> 4) * 4, cc = l & 15;
  #pragma unroll
  for (int mi = 0; mi < 4; ++mi)
    #pragma unroll
    for (int ni = 0; ni < 2; ++ni)
      #pragma unroll
      for (int r = 0; r < 4; ++r) {
        int row = m0 + wm + mi * 16 + rr + r;
        int col = nloc + wn + ni * 16 + cc;
        O[(size_t)row * DIM + col] = (bf16)acc[mi][ni][r];
      }
}

// ================= Kernel B: scores = scale * q @ k^T =================
// grid (66, 8): 66 kv-tiles of 64 (0..63 from k_cache fp32, 64..65 from k_new bf16)
__global__ __launch_bounds__(256) void k_scores(const bf16* __restrict__ qb,
    const bf16* __restrict__ kb, const float* __restrict__ kcache,
    float* __restrict__ scores) {
  __shared__ bf16 As[128 * 64];
  __shared__ bf16 Bs[64 * 64];
  const int nt = blockIdx.x;
  const int b  = blockIdx.y;
  const int tid = threadIdx.x;
  const int l = tid & 63, wid = tid >> 6;
  const int wm = (wid >> 1) * 64, wn = (wid & 1) * 32;
  const bf16* Q = qb + (size_t)b * BQ * DIM;
  f32x4 acc[4][2] = {};
  for (int kt = 0; kt < DIM / 64; ++kt) {
    const int k0 = kt * 64;
    __syncthreads();
    stage_bf16<128, 256>(Q + k0, DIM, As, tid);
    if (nt < 64)
      stage_f32<64, 256>(kcache + ((size_t)b * KVL + nt * 64) * DIM + k0, DIM, Bs, tid);
    else
      stage_bf16<64, 256>(kb + ((size_t)b * BQ + (nt - 64) * 64) * DIM + k0, DIM, Bs, tid);
    __syncthreads();
    mma_tile<4, 2>(As, Bs, acc, l, wm, wn);
  }
  const float scale = 0.022097086912079608f;  // 1/sqrt(2048)
  const int rr = (l >> 4) * 4, cc = l & 15;
  #pragma unroll
  for (int mi = 0; mi < 4; ++mi)
    #pragma unroll
    for (int ni = 0; ni < 2; ++ni)
      #pragma unroll
      for (int r = 0; r < 4; ++r) {
        int row = wm + mi * 16 + rr + r;
        int col = nt * 64 + wn + ni * 16 + cc;
        scores[((size_t)b * BQ + row) * KVT + col] = acc[mi][ni][r] * scale;
      }
}

// ================= Kernel C: row softmax -> bf16 attn =================
__global__ __launch_bounds__(256) void k_softmax(const float* __restrict__ scores,
                                                 bf16* __restrict__ attn) {
  __shared__ float s[KVT];
  __shared__ float red[8];
  const int row = blockIdx.x;           // 0..1023
  const int tid = threadIdx.x;
  const size_t base = (size_t)row * KVT;
  float lm = -1e30f;
  for (int i = tid; i < KVT; i += 256) {
    float v = scores[base + i];
    s[i] = v;
    lm = fmaxf(lm, v);
  }
  #pragma unroll
  for (int off = 32; off >= 1; off >>= 1) lm = fmaxf(lm, __shfl_xor(lm, off, 64));
  if ((tid & 63) == 0) red[tid >> 6] = lm;
  __syncthreads();
  const float m = fmaxf(fmaxf(red[0], red[1]), fmaxf(red[2], red[3]));
  float ls = 0.f;
  for (int i = tid; i < KVT; i += 256) {
    float e = __expf(s[i] - m);
    s[i] = e;
    ls += e;
  }
  #pragma unroll
  for (int off = 32; off >= 1; off >>= 1) ls += __shfl_xor(ls, off, 64);
  if ((tid & 63) == 0) red[4 + (tid >> 6)] = ls;
  __syncthreads();
  const float inv = 1.f / (red[4] + red[5] + red[6] + red[7]);
  for (int i = tid; i < KVT; i += 256) attn[base + i] = (bf16)(s[i] * inv);
}

// ================= Kernel D: out = attn @ V =================
// grid (32, 8): 32 n-tiles of 64 over DIM. K = 4224 (66 k-tiles; last 2 = v_new).
// V tile is transpose-staged into LDS as VT[n][k].
__global__ __launch_bounds__(512) void k_pv(const bf16* __restrict__ attn,
    const float* __restrict__ vcache, const bf16* __restrict__ vb,
    bf16* __restrict__ ob) {
  __shared__ bf16 As[128 * 64];
  __shared__ bf16 VT[64 * 64];
  const int nt = blockIdx.x;
  const int b  = blockIdx.y;
  const int n0 = nt * 64;
  const int tid = threadIdx.x;
  const int l = tid & 63, wid = tid >> 6;         // 8 waves
  const int wm = (wid & 3) * 32, wn = (wid >> 2) * 32;
  f32x4 acc[2][2] = {};
  const int vn = tid & 63;
  const int vk = (tid >> 6) * 8;
  for (int kt = 0; kt < KVT / 64; ++kt) {
    const int k0 = kt * 64;
    __syncthreads();
    stage_bf16<128, 512>(attn + (size_t)b * BQ * KVT + k0, KVT, As, tid);
    if (kt < 64) {
      const float* src = vcache + ((size_t)b * KVL + k0) * DIM + n0 + vn;
      #pragma unroll
      for (int j = 0; j < 2; ++j) {
        int kl = vk + j * 4;
        bf16x4 t;
        #pragma unroll
        for (int i = 0; i < 4; ++i) t[i] = (bf16)src[(size_t)(kl + i) * DIM];
        *reinterpret_cast<bf16x4*>(VT + swz(vn, kl)) = t;
      }
    } else {
      const bf16* src = vb + ((size_t)b * BQ + (k0 - KVL)) * DIM + n0 + vn;
      #pragma unroll
      for (int j = 0; j < 2; ++j) {
        int kl = vk + j * 4;
        bf16x4 t;
        #pragma unroll
        for (int i = 0; i < 4; ++i) t[i] = src[(size_t)(kl + i) * DIM];
        *reinterpret_cast<bf16x4*>(VT + swz(vn, kl)) = t;
      }
    }
    __syncthreads();
    mma_tile<2, 2>(As, VT, acc, l, wm, wn);
  }
  const int rr = (l >> 4) * 4, cc = l & 15;
  #pragma unroll
  for (int mi = 0; mi < 2; ++mi)
    #pragma unroll
    for (int ni = 0; ni < 2; ++ni)
      #pragma unroll
      for (int r = 0; r < 4; ++r) {
        int row = wm + mi * 16 + rr + r;
        int col = n0 + wn + ni * 16 + cc;
        ob[((size_t)b * BQ + row) * DIM + col] = (bf16)acc[mi][ni][r];
      }
}

// ================= Kernel E: final = out @ wo^T (fp32 result) =================
// grid (32, 16): 64x64 tiles.
__global__ __launch_bounds__(256) void k_oproj(const bf16* __restrict__ ob,
    const float* __restrict__ wo, float* __restrict__ out) {
  __shared__ bf16 As[64 * 64];
  __shared__ bf16 Bs[64 * 64];
  const int nt = blockIdx.x;
  const int mt = blockIdx.y;
  const int m0 = mt * 64, n0 = nt * 64;
  const int tid = threadIdx.x;
  const int l = tid & 63, wid = tid >> 6;
  const int wm = (wid & 1) * 32, wn = (wid >> 1) * 32;
  f32x4 acc[2][2] = {};
  for (int kt = 0; kt < DIM / 64; ++kt) {
    const int k0 = kt * 64;
    __syncthreads();
    stage_bf16<64, 256>(ob + (size_t)m0 * DIM + k0, DIM, As, tid);
    stage_f32<64, 256>(wo + (size_t)n0 * DIM + k0, DIM, Bs, tid);
    __syncthreads();
    mma_tile<2, 2>(As, Bs, acc, l, wm, wn);
  }
  const int rr = (l >> 4) * 4, cc = l & 15;
  #pragma unroll
  for (int mi = 0; mi < 2; ++mi)
    #pragma unroll
    for (int ni = 0; ni < 2; ++ni)
      #pragma unroll
      for (int r = 0; r < 4; ++r) {
        int row = m0 + wm + mi * 16 + rr + r;
        int col = n0 + wn + ni * 16 + cc;
        out[(size_t)row * DIM + col] = acc[mi][ni][r];
      }
}

extern "C" void kernel_launch(void* const* d_in, const int* in_sizes, int n_in,
                              void* d_out, int out_size, void* d_ws, size_t ws_size,
                              hipStream_t stream) {
  const float* x      = (const float*)d_in[0];
  // d_in[1] = mask (unused by the reference forward)
  const float* kcache = (const float*)d_in[2];
  const float* vcache = (const float*)d_in[3];
  const float* wq     = (const float*)d_in[4];
  const float* wk     = (const float*)d_in[5];
  const float* wv     = (const float*)d_in[6];
  const float* wo     = (const float*)d_in[7];
  float* out = (float*)d_out;

  char* ws = (char*)d_ws;
  bf16*  qb     = (bf16*)(ws + 0);                    //  4 MB  [1024][2048]
  bf16*  kb     = (bf16*)(ws + 4194304);              //  4 MB
  bf16*  vb     = (bf16*)(ws + 8388608);              //  4 MB
  float* scores = (float*)(ws + 12582912);            // 17.3 MB [1024][4224]
  bf16*  attnb  = (bf16*)(ws + 29884416);             //  8.65 MB
  bf16*  obuf   = (bf16*)(ws + 38535168);             //  4 MB

  k_qkv<<<dim3(96, 8), 256, 0, stream>>>(x, wq, wk, wv, qb, kb, vb);
  k_scores<<<dim3(66, 8), 256, 0, stream>>>(qb, kb, kcache, scores);
  k_softmax<<<dim3(1024), 256, 0, stream>>>(scores, attnb);
  k_pv<<<dim3(32, 8), 512, 0, stream>>>(attnb, vcache, vb, obuf);
  k_oproj<<<dim3(32, 16), 256, 0, stream>>>(obuf, wo, out);
}